// Round 10
// baseline (316.489 us; speedup 1.0000x reference)
//
#include <hip/hip_runtime.h>
#include <math.h>

// ---------------------------------------------------------------------------
// DCN_Align on MI355X. Convs AND deformable conv on MFMA bf16 (16x16x32).
// Big 192-res stride-1 convs: rolling-row sweep, YS=2, HALF-SPLIT (wave =
// 16 couts; pass-0 A cached in VGPRs). DCN: conv_om fused; phase-2 per-tap
// sequential (round-8 form -- the precompute-all variant spilled).
// ---------------------------------------------------------------------------

#define BDIM 256

typedef __attribute__((ext_vector_type(8))) short short8v;
typedef __attribute__((ext_vector_type(4))) float f32x4;

__device__ __forceinline__ unsigned short f2bf(float f) {
    unsigned u = __builtin_bit_cast(unsigned, f);
    u = (u + 0x7FFF + ((u >> 16) & 1)) >> 16;   // round-to-nearest-even
    return (unsigned short)u;
}
__device__ __forceinline__ float bf2f(unsigned short h) {
    unsigned u = ((unsigned)h) << 16;
    return __builtin_bit_cast(float, u);
}

// ---------------------------------------------------------------------------
// Rolling-row MFMA conv, stride 1, Hin==Hout==H, 32 couts total, HALF-SPLIT:
// wave (wid&1) computes couts [h*16, h*16+16). Pass-0 A cached (9 frags);
// pass-1 A per-use (L1-hot). 3-row B-window rolls; 3 loads/row/pass.
template<int NPASS, bool LRELU, int YS>
__global__ __launch_bounds__(BDIM, NPASS == 1 ? 4 : 3)
void convr_k(const short* __restrict__ in0, const short* __restrict__ in1,
             const short* __restrict__ wf,   // [pass][tap][2][lane][8] bf16
             const float* __restrict__ bias,
             short* __restrict__ out, int H, int W)
{
    const int lane = threadIdx.x & 63;
    const int wid  = blockIdx.x * 4 + (threadIdx.x >> 6);
    const int hh   = wid & 1;          // cout half
    const int sw   = wid >> 1;         // spatial wave id
    const int segs = W >> 4;
    const int strips = (H / YS) * segs;
    const int b = sw / strips;
    int r = sw - b * strips;
    const int ys = r / segs;
    const int y0 = ys * YS;
    const int x0 = (r - ys * segs) * 16;
    const int lp = lane & 15;
    const int g  = lane >> 4;

    int colOff[3]; bool colOk[3];
#pragma unroll
    for (int tx = 0; tx < 3; ++tx) {
        const int ix = x0 + lp + tx - 1;
        colOk[tx] = (unsigned)ix < (unsigned)W;
        colOff[tx] = min(max(ix, 0), W - 1) * 32 + g * 8;
    }

    const size_t inPlane = (size_t)H * W * 32;
    const short8v zero = {};
    const short* inp0 = in0 + (size_t)b * inPlane;
    const short* inp1 = (NPASS > 1) ? in1 + (size_t)b * inPlane : nullptr;

    // pass-0 A-frags for this half, cached (9 x 4 VGPR)
    short8v awc[9];
#pragma unroll
    for (int t = 0; t < 9; ++t)
        awc[t] = *(const short8v*)(wf + (((size_t)t * 2 + hh) * 64 + lane) * 8);

    short8v win[NPASS][3][3];

#define LOADROW(SLOT, IY) do {                                                \
        const int iy_ = (IY);                                                 \
        const bool rok_ = (unsigned)iy_ < (unsigned)H;                        \
        const int ro_ = min(max(iy_, 0), H - 1) * W;                          \
        _Pragma("unroll")                                                     \
        for (int tx = 0; tx < 3; ++tx) {                                      \
            short8v v_ = *(const short8v*)(inp0 + (size_t)ro_ * 32 + colOff[tx]); \
            win[0][SLOT][tx] = (rok_ & colOk[tx]) ? v_ : zero;                \
            if constexpr (NPASS > 1) {                                        \
                short8v w_ = *(const short8v*)(inp1 + (size_t)ro_ * 32 + colOff[tx]); \
                win[1][SLOT][tx] = (rok_ & colOk[tx]) ? w_ : zero;            \
            }                                                                 \
        }                                                                     \
    } while (0)

    LOADROW(0, y0 - 1);
    LOADROW(1, y0);

#pragma unroll
    for (int s = 0; s < YS; ++s) {
        LOADROW((s + 2) % 3, y0 + s + 1);

        f32x4 a0 = (f32x4){0.f, 0.f, 0.f, 0.f};
#pragma unroll
        for (int p = 0; p < NPASS; ++p) {
#pragma unroll
            for (int ty = 0; ty < 3; ++ty) {
#pragma unroll
                for (int tx = 0; tx < 3; ++tx) {
                    const int t = ty * 3 + tx;
                    const short8v bv = win[p][(s + ty) % 3][tx];
                    short8v av;
                    if (p == 0) {
                        av = awc[t];
                    } else {
                        av = *(const short8v*)(
                            wf + ((((size_t)9 + t) * 2 + hh) * 64 + lane) * 8);
                    }
                    a0 = __builtin_amdgcn_mfma_f32_16x16x32_bf16(av, bv, a0, 0, 0, 0);
                }
            }
        }

        short* op = out + (((size_t)b * H + (y0 + s)) * W + x0 + lp) * 32;
        ushort4 st0;
#pragma unroll
        for (int j = 0; j < 4; ++j) {
            float v0 = a0[j] + bias[hh * 16 + g * 4 + j];
            if (LRELU) v0 = (v0 >= 0.f) ? v0 : 0.1f * v0;
            ((unsigned short*)&st0)[j] = f2bf(v0);
        }
        *(ushort4*)(op + hh * 16 + g * 4) = st0;
    }
#undef LOADROW
}

// ---------------------------------------------------------------------------
// Upfront-9-tap MFMA conv (small resolutions / strided).
template<int NPASS, int NHALF, int STRIDE, bool LRELU>
__global__ __launch_bounds__(BDIM, 4)
void convm_k(const short* __restrict__ in0, const short* __restrict__ in1,
             const short* __restrict__ wf,
             const float* __restrict__ bias,
             short* __restrict__ out,
             int Hin, int Win, int Hout, int Wout, int OCS)
{
    const int lane = threadIdx.x & 63;
    const int wid  = blockIdx.x * 4 + (threadIdx.x >> 6);
    const int segs = Wout >> 4;
    const int b  = wid / (Hout * segs);
    int r = wid - b * (Hout * segs);
    const int oy = r / segs;
    const int x0 = (r - oy * segs) * 16;
    const int lp = lane & 15;
    const int g  = lane >> 4;

    int rowOff[3]; bool rowOk[3];
#pragma unroll
    for (int ty = 0; ty < 3; ++ty) {
        const int iy = oy * STRIDE + ty - 1;
        rowOk[ty] = (unsigned)iy < (unsigned)Hin;
        rowOff[ty] = min(max(iy, 0), Hin - 1) * Win;
    }
    int colOff[3]; bool colOk[3];
#pragma unroll
    for (int tx = 0; tx < 3; ++tx) {
        const int ix = (x0 + lp) * STRIDE + tx - 1;
        colOk[tx] = (unsigned)ix < (unsigned)Win;
        colOff[tx] = min(max(ix, 0), Win - 1) * 32 + g * 8;
    }

    f32x4 acc[NHALF];
#pragma unroll
    for (int h = 0; h < NHALF; ++h) acc[h] = (f32x4){0.f, 0.f, 0.f, 0.f};

    const size_t inPlane = (size_t)Hin * Win * 32;
    const short8v zero = {};

#pragma unroll
    for (int pass = 0; pass < NPASS; ++pass) {
        const short* inp = (pass == 0 ? in0 : in1) + (size_t)b * inPlane;

        short8v bv[9];
#pragma unroll
        for (int t = 0; t < 9; ++t) {
            const int ty = t / 3, tx = t % 3;
            short8v v = *(const short8v*)(inp + (size_t)rowOff[ty] * 32 + colOff[tx]);
            bv[t] = (rowOk[ty] & colOk[tx]) ? v : zero;
        }
#pragma unroll
        for (int t = 0; t < 9; ++t) {
#pragma unroll
            for (int h = 0; h < NHALF; ++h) {
                short8v av = *(const short8v*)(
                    wf + ((((size_t)pass * 9 + t) * NHALF + h) * 64 + lane) * 8);
                acc[h] = __builtin_amdgcn_mfma_f32_16x16x32_bf16(av, bv[t], acc[h], 0, 0, 0);
            }
        }
    }

    short* op = out + (((size_t)b * Hout + oy) * Wout + x0 + lp) * OCS;
#pragma unroll
    for (int h = 0; h < NHALF; ++h) {
        const int co0 = h * 16 + g * 4;
        ushort4 st;
#pragma unroll
        for (int j = 0; j < 4; ++j) {
            float v = acc[h][j] + bias[co0 + j];
            if (LRELU) v = (v >= 0.f) ? v : 0.1f * v;
            ((unsigned short*)&st)[j] = f2bf(v);
        }
        *(ushort4*)(op + co0) = st;
    }
}

// ---------------------------------------------------------------------------
// Weight prep: [O][I][3][3] fp32 -> fragment layout bf16 [pass][t][h][lane][8].
struct WPArgs {
    const float* src[11];
    int off[11];      // dst offset in shorts
    int npass[11], nhalf[11], O[11];
};

__global__ __launch_bounds__(BDIM)
void wprep_k(WPArgs a, short* __restrict__ wbase)
{
    const int z = blockIdx.z;
    const int n = a.npass[z] * 9 * a.nhalf[z] * 512;
    const int idx = blockIdx.x * BDIM + threadIdx.x;
    if (idx >= n) return;
    const int j = idx & 7;
    const int l = (idx >> 3) & 63;
    int r = idx >> 9;
    const int h = r % a.nhalf[z]; r /= a.nhalf[z];
    const int t = r % 9;
    const int pass = r / 9;
    const int I = a.npass[z] * 32;
    const int cout = h * 16 + (l & 15);
    const int cin  = pass * 32 + (l >> 4) * 8 + j;
    float v = (cout < a.O[z]) ? a.src[z][((size_t)cout * I + cin) * 9 + t] : 0.f;
    wbase[a.off[z] + idx] = (short)f2bf(v);
}

// dcn weights [32o][32i][3][3] -> [tap][half][lane][8] bf16 frags
__global__ __launch_bounds__(BDIM)
void wdp_k(const float* __restrict__ w, short* __restrict__ dst)
{
    const int idx = blockIdx.x * BDIM + threadIdx.x;
    if (idx >= 9 * 2 * 64 * 8) return;
    const int j = idx & 7;
    const int l = (idx >> 3) & 63;
    const int h = (idx >> 9) & 1;
    const int k = idx >> 10;
    const int cout = h * 16 + (l & 15);
    const int cin  = (l >> 4) * 8 + j;
    dst[idx] = (short)f2bf(w[((size_t)cout * 32 + cin) * 9 + k]);
}

// fea NCHW fp32 -> NHWC bf16 (two tensors in one launch via z)
__global__ __launch_bounds__(BDIM)
void cvtnhwc_k(const float* __restrict__ s0, const float* __restrict__ s1,
               short* __restrict__ d0, short* __restrict__ d1, int H, int W)
{
    const float* s = blockIdx.z ? s1 : s0;
    short* d = blockIdx.z ? d1 : d0;
    const int idx = blockIdx.x * BDIM + threadIdx.x;
    if (idx >= 4 * 32 * H * W) return;
    const int c = idx & 31;
    int t = idx >> 5;
    const int x = t % W; t /= W;
    const int y = t % H;
    const int b = t / H;
    d[idx] = (short)f2bf(s[(((size_t)b * 32 + c) * H + y) * W + x]);
}

// Bilinear 2x upsample, NHWC bf16, half-pixel centers, edge clamp.
__global__ __launch_bounds__(BDIM)
void up2b_k(const short* __restrict__ in, short* __restrict__ out,
            int Hin, int Win)
{
    const int Hout = 2 * Hin, Wout = 2 * Win;
    const int idx = blockIdx.x * BDIM + threadIdx.x;
    if (idx >= 4 * Hout * Wout * 4) return;
    const int cg = idx & 3;
    int t = idx >> 2;
    const int x = t % Wout; t /= Wout;
    const int y = t % Hout;
    const int b = t / Hout;

    const float sy = (y + 0.5f) * 0.5f - 0.5f;
    const float sx = (x + 0.5f) * 0.5f - 0.5f;
    const float y0f = floorf(sy), x0f = floorf(sx);
    const float wy = sy - y0f, wx = sx - x0f;
    const int y0 = (int)y0f, x0 = (int)x0f;
    const int y0c = min(max(y0, 0), Hin - 1);
    const int y1c = min(max(y0 + 1, 0), Hin - 1);
    const int x0c = min(max(x0, 0), Win - 1);
    const int x1c = min(max(x0 + 1, 0), Win - 1);

    const short* base = in + (size_t)b * Hin * Win * 32 + cg * 8;
    short8v v00 = *(const short8v*)(base + ((size_t)y0c * Win + x0c) * 32);
    short8v v01 = *(const short8v*)(base + ((size_t)y0c * Win + x1c) * 32);
    short8v v10 = *(const short8v*)(base + ((size_t)y1c * Win + x0c) * 32);
    short8v v11 = *(const short8v*)(base + ((size_t)y1c * Win + x1c) * 32);

    short8v o;
#pragma unroll
    for (int j = 0; j < 8; ++j) {
        float f = (1.f - wy) * ((1.f - wx) * bf2f((unsigned short)v00[j]) +
                                wx * bf2f((unsigned short)v01[j]))
                + wy * ((1.f - wx) * bf2f((unsigned short)v10[j]) +
                        wx * bf2f((unsigned short)v11[j]));
        o[j] = (short)f2bf(f);
    }
    short* op = out + (size_t)b * Hout * Wout * 32 + ((size_t)y * Wout + x) * 32 + cg * 8;
    *(short8v*)op = o;
}

// ---------------------------------------------------------------------------
// Fused conv_om + modulated deformable conv (DCNv2) on MFMA.
// Phase 1: om = conv3x3(base_offset) on MFMA -> LDS [wave][16][116]
// (wave-private, padded). Phase 2 (round-8 sequential form): per tap
// address -> 4 gathers -> blend -> 2 MFMAs.
__global__ __launch_bounds__(BDIM, 4)
void dcnm_k(const short* __restrict__ xb,    // fea2 NHWC bf16 [B][H][W][32]
            const short* __restrict__ bo,    // base_offset NHWC bf16
            const short* __restrict__ wfo,   // om A-frags [9][7][64][8]
            const float* __restrict__ obias, // om bias (108)
            const short* __restrict__ wfd,   // dcn A-frags [9][2][64][8]
            const float* __restrict__ bias,  // dcn bias (32)
            float* __restrict__ out, int H, int W)
{
    __shared__ unsigned short omld[4][16][116];   // padded stride

    const int lane = threadIdx.x & 63;
    const int wv   = threadIdx.x >> 6;
    const int wid  = blockIdx.x * 4 + wv;
    const int segs = W >> 4;
    const int b = wid / (H * segs);
    int r = wid - b * (H * segs);
    const int y = r / segs;
    const int x0 = (r - y * segs) * 16;
    const int lp = lane & 15;
    const int g  = lane >> 4;
    const int x  = x0 + lp;
    const size_t plane = (size_t)H * W;
    const short8v zero = {};

    // ---------------- phase 1: om = conv_om(base_offset) ----------------
    {
        int rowOff[3]; bool rowOk[3];
#pragma unroll
        for (int ty = 0; ty < 3; ++ty) {
            const int iy = y + ty - 1;
            rowOk[ty] = (unsigned)iy < (unsigned)H;
            rowOff[ty] = min(max(iy, 0), H - 1) * W;
        }
        int colOff[3]; bool colOk[3];
#pragma unroll
        for (int tx = 0; tx < 3; ++tx) {
            const int ix = x + tx - 1;
            colOk[tx] = (unsigned)ix < (unsigned)W;
            colOff[tx] = min(max(ix, 0), W - 1) * 32 + g * 8;
        }
        const short* inp = bo + (size_t)b * plane * 32;
        short8v bv[9];
#pragma unroll
        for (int t = 0; t < 9; ++t) {
            const int ty = t / 3, tx = t % 3;
            short8v v = *(const short8v*)(inp + (size_t)rowOff[ty] * 32 + colOff[tx]);
            bv[t] = (rowOk[ty] & colOk[tx]) ? v : zero;
        }
        f32x4 acc[7];
#pragma unroll
        for (int h = 0; h < 7; ++h) acc[h] = (f32x4){0.f, 0.f, 0.f, 0.f};
#pragma unroll
        for (int t = 0; t < 9; ++t) {
#pragma unroll
            for (int h = 0; h < 7; ++h) {
                short8v av = *(const short8v*)(wfo + (((size_t)t * 7 + h) * 64 + lane) * 8);
                acc[h] = __builtin_amdgcn_mfma_f32_16x16x32_bf16(av, bv[t], acc[h], 0, 0, 0);
            }
        }
#pragma unroll
        for (int h = 0; h < 7; ++h) {
            const int co0 = h * 16 + g * 4;
            ushort4 st;
#pragma unroll
            for (int j = 0; j < 4; ++j)
                ((unsigned short*)&st)[j] = f2bf(acc[h][j] + obias[min(co0 + j, 107)]);
            *(ushort4*)&omld[wv][lp][co0] = st;
        }
    }
    // wave-private LDS: in-wave ds ordering + compiler lgkmcnt suffice

    // ---------------- phase 2: deformable sampling + PV ----------------
    f32x4 p0 = (f32x4){0.f, 0.f, 0.f, 0.f};
    f32x4 p1 = (f32x4){0.f, 0.f, 0.f, 0.f};
    const short* xbb = xb + (size_t)b * plane * 32 + g * 8;

#pragma unroll
    for (int k = 0; k < 9; ++k) {
        const float offy = bf2f(omld[wv][lp][g * 9 + k]);
        const float offx = bf2f(omld[wv][lp][36 + g * 9 + k]);
        const float ml   = bf2f(omld[wv][lp][72 + g * 9 + k]);
        const float m = 1.f / (1.f + __expf(-ml));

        const float py = offy + (float)y + (float)(k / 3 - 1);
        const float px = offx + (float)x + (float)(k % 3 - 1);
        const float y0f = floorf(py), x0f = floorf(px);
        const int y0 = (int)y0f, x0i = (int)x0f;
        const float wy1 = py - y0f, wx1 = px - x0f;
        const float wy0 = 1.f - wy1, wx0 = 1.f - wx1;

        const bool y0ok = (unsigned)y0 < (unsigned)H;
        const bool y1ok = (unsigned)(y0 + 1) < (unsigned)H;
        const bool x0ok = (unsigned)x0i < (unsigned)W;
        const bool x1ok = (unsigned)(x0i + 1) < (unsigned)W;
        const int y0c = min(max(y0, 0), H - 1);
        const int y1c = min(max(y0 + 1, 0), H - 1);
        const int x0c = min(max(x0i, 0), W - 1);
        const int x1c = min(max(x0i + 1, 0), W - 1);

        const float w00 = wy0 * wx0 * ((y0ok && x0ok) ? 1.f : 0.f) * m;
        const float w01 = wy0 * wx1 * ((y0ok && x1ok) ? 1.f : 0.f) * m;
        const float w10 = wy1 * wx0 * ((y1ok && x0ok) ? 1.f : 0.f) * m;
        const float w11 = wy1 * wx1 * ((y1ok && x1ok) ? 1.f : 0.f) * m;

        short8v v00 = *(const short8v*)(xbb + ((size_t)y0c * W + x0c) * 32);
        short8v v01 = *(const short8v*)(xbb + ((size_t)y0c * W + x1c) * 32);
        short8v v10 = *(const short8v*)(xbb + ((size_t)y1c * W + x0c) * 32);
        short8v v11 = *(const short8v*)(xbb + ((size_t)y1c * W + x1c) * 32);

        short8v bv;
#pragma unroll
        for (int j = 0; j < 8; ++j) {
            float s = w00 * bf2f((unsigned short)v00[j])
                    + w01 * bf2f((unsigned short)v01[j])
                    + w10 * bf2f((unsigned short)v10[j])
                    + w11 * bf2f((unsigned short)v11[j]);
            bv[j] = (short)f2bf(s);
        }

        short8v a0 = *(const short8v*)(wfd + (((size_t)k * 2 + 0) * 64 + lane) * 8);
        short8v a1 = *(const short8v*)(wfd + (((size_t)k * 2 + 1) * 64 + lane) * 8);
        p0 = __builtin_amdgcn_mfma_f32_16x16x32_bf16(a0, bv, p0, 0, 0, 0);
        p1 = __builtin_amdgcn_mfma_f32_16x16x32_bf16(a1, bv, p1, 0, 0, 0);
    }

    float* op = out + (size_t)b * 32 * plane + (size_t)y * W + x;
#pragma unroll
    for (int j = 0; j < 4; ++j) {
        const int co0 = g * 4 + j;
        const int co1 = 16 + g * 4 + j;
        op[(size_t)co0 * plane] = p0[j] + bias[co0];
        op[(size_t)co1 * plane] = p1[j] + bias[co1];
    }
}

// ---------------------------------------------------------------------------

extern "C" void kernel_launch(void* const* d_in, const int* in_sizes, int n_in,
                              void* d_out, int out_size, void* d_ws, size_t ws_size,
                              hipStream_t stream)
{
    const float* fea1  = (const float*)d_in[0];
    const float* fea2  = (const float*)d_in[1];
    const float* w1_1  = (const float*)d_in[2];  const float* b1_1 = (const float*)d_in[3];
    const float* w2_1  = (const float*)d_in[4];  const float* b2_1 = (const float*)d_in[5];
    const float* w3_1  = (const float*)d_in[6];  const float* b3_1 = (const float*)d_in[7];
    const float* w4_1  = (const float*)d_in[8];  const float* b4_1 = (const float*)d_in[9];
    const float* w6_1  = (const float*)d_in[10]; const float* b6_1 = (const float*)d_in[11];
    const float* w7_1  = (const float*)d_in[12]; const float* b7_1 = (const float*)d_in[13];
    const float* w1_2  = (const float*)d_in[14]; const float* b1_2 = (const float*)d_in[15];
    const float* w2_2  = (const float*)d_in[16]; const float* b2_2 = (const float*)d_in[17];
    const float* w3_2  = (const float*)d_in[18]; const float* b3_2 = (const float*)d_in[19];
    const float* w4_2  = (const float*)d_in[20]; const float* b4_2 = (const float*)d_in[21];
    const float* w_om  = (const float*)d_in[22]; const float* b_om = (const float*)d_in[23];
    const float* w_dcn = (const float*)d_in[24]; const float* b_dcn= (const float*)d_in[25];

    const int H = 192, W = 192;
    char* ws = (char*)d_ws;

    // byte offsets; fea2b stays live to the end (dcnm samples it)
    short* fea1b = (short*)(ws + 0);          // bf16 NHWC 192  (9.44 MB)
    short* fea2b = (short*)(ws + 9437184);    // LIVE TO END
    short* bufA  = (short*)(ws + 18874368);   // off      192
    short* bufB  = (short*)(ws + 28311552);   // off1     192 (lives to conv3_2)
    short* bufC  = (short*)(ws + 0);          // off2a    96  (fea1b dead)
    short* bufD  = (short*)(ws + 2359296);    // off2     96
    short* bufE  = (short*)(ws + 4718592);    // off3a    48
    short* bufF  = (short*)(ws + 5308416);    // off3     48
    short* bufG  = (short*)(ws + 5898240);    // up96     96
    short* bufH  = (short*)(ws + 0);          // conv1_2 out 96 (bufC dead)
    short* bufI  = (short*)(ws + 4718592);    // conv2_2 out 96 (E/F dead)
    short* bufJ  = (short*)(ws + 37748736);   // up192
    short* bufK  = (short*)(ws + 18874368);   // conv3_2 out (bufA dead)
    short* bufL  = (short*)(ws + 0);          // base_offset 192 (H/D/I dead)
    short* wfrag = (short*)(ws + 70778880);   // conv weight frags (304128 B)
    short* wfdcn = (short*)(ws + 71083008);   // dcn weight frags (18432 B)

    // fragment offsets in shorts per conv (om entry has nh=7 -> 32256 shorts)
    const int WOFF[11] = {0, 18432, 27648, 36864, 46080, 55296,
                          64512, 82944, 92160, 110592, 119808};

    dim3 blk(BDIM, 1, 1);

    // 0. weight prep + input conversions
    {
        WPArgs a;
        const float* srcs[11] = {w1_1, w2_1, w3_1, w4_1, w6_1, w7_1,
                                 w1_2, w2_2, w3_2, w4_2, w_om};
        const int NP[11] = {2,1,1,1,1,1,2,1,2,1,1};
        const int NH[11] = {2,2,2,2,2,2,2,2,2,2,7};
        const int Os[11] = {32,32,32,32,32,32,32,32,32,32,108};
        for (int i = 0; i < 11; ++i) {
            a.src[i] = srcs[i]; a.off[i] = WOFF[i];
            a.npass[i] = NP[i]; a.nhalf[i] = NH[i]; a.O[i] = Os[i];
        }
        wprep_k<<<dim3(126, 1, 11), blk, 0, stream>>>(a, wfrag);
        cvtnhwc_k<<<dim3(18432, 1, 2), blk, 0, stream>>>(fea1, fea2, fea1b, fea2b, H, W);
        wdp_k<<<dim3(36), blk, 0, stream>>>(w_dcn, wfdcn);
    }

    // 192-res rolling convs: waves = B*(H/2)*12*2 halves = 9216 -> 2304 blocks
    // 1. off = lrelu(conv1_1(cat(fea1, fea2)))           192  [rolling, half-split]
    convr_k<2,true,2><<<dim3(2304), blk, 0, stream>>>(
        fea1b, fea2b, wfrag + WOFF[0], b1_1, bufA, 192, 192);
    // 2. off1 = lrelu(conv2_1(off))                      192
    convr_k<1,true,2><<<dim3(2304), blk, 0, stream>>>(
        bufA, nullptr, wfrag + WOFF[1], b2_1, bufB, 192, 192);
    // 3. off2a = lrelu(conv3_1(off1, s2))                96
    convm_k<1,2,2,true><<<dim3(576), blk, 0, stream>>>(
        bufB, nullptr, wfrag + WOFF[2], b3_1, bufC, 192,192,96,96, 32);
    // 4. off2 = lrelu(conv4_1(off2a))                    96
    convm_k<1,2,1,true><<<dim3(576), blk, 0, stream>>>(
        bufC, nullptr, wfrag + WOFF[3], b4_1, bufD, 96,96,96,96, 32);
    // 5. off3a = lrelu(conv6_1(off2, s2))                48
    convm_k<1,2,2,true><<<dim3(144), blk, 0, stream>>>(
        bufD, nullptr, wfrag + WOFF[4], b6_1, bufE, 96,96,48,48, 32);
    // 6. off3 = lrelu(conv7_1(off3a))                    48
    convm_k<1,2,1,true><<<dim3(144), blk, 0, stream>>>(
        bufE, nullptr, wfrag + WOFF[5], b7_1, bufF, 48,48,48,48, 32);
    // 7. up96 = up2(off3)
    up2b_k<<<dim3(576), blk, 0, stream>>>(bufF, bufG, 48, 48);
    // 8. t = lrelu(conv1_2(cat(up96, off2)))             96
    convm_k<2,2,1,true><<<dim3(576), blk, 0, stream>>>(
        bufG, bufD, wfrag + WOFF[6], b1_2, bufH, 96,96,96,96, 32);
    // 9. t2 = lrelu(conv2_2(t))                          96
    convm_k<1,2,1,true><<<dim3(576), blk, 0, stream>>>(
        bufH, nullptr, wfrag + WOFF[7], b2_2, bufI, 96,96,96,96, 32);
    // 10. up192 = up2(t2)
    up2b_k<<<dim3(2304), blk, 0, stream>>>(bufI, bufJ, 96, 96);
    // 11. off = lrelu(conv3_2(cat(up192, off1)))         192
    convr_k<2,true,2><<<dim3(2304), blk, 0, stream>>>(
        bufJ, bufB, wfrag + WOFF[8], b3_2, bufK, 192, 192);
    // 12. base_offset = conv4_2(off)    (no lrelu)       192
    convr_k<1,false,2><<<dim3(2304), blk, 0, stream>>>(
        bufK, nullptr, wfrag + WOFF[9], b4_2, bufL, 192, 192);
    // 13. out = deform_conv(fea2, conv_om(base_offset))  [fused]
    dcnm_k<<<dim3(2304), blk, 0, stream>>>(
        fea2b, bufL, wfrag + WOFF[10], b_om, wfdcn, b_dcn, (float*)d_out, H, W);
}

// Round 11
// 299.861 us; speedup vs baseline: 1.0555x; 1.0555x over previous
//
#include <hip/hip_runtime.h>
#include <math.h>

// ---------------------------------------------------------------------------
// DCN_Align on MI355X. Convs AND deformable conv on MFMA bf16 (16x16x32).
// Big 192-res stride-1 convs: rolling-row sweep with DISTANCE-1 prefetch
// (4-slot row window, YS=4, half-split couts, per-pass A in VGPRs).
// DCN: conv_om fused; phase-2 per-tap sequential; bf16 packing via
// v_cvt_pk_bf16_f32.
// ---------------------------------------------------------------------------

#define BDIM 256

typedef __attribute__((ext_vector_type(8))) short short8v;
typedef __attribute__((ext_vector_type(4))) float f32x4;

__device__ __forceinline__ unsigned short f2bf(float f) {
    unsigned u = __builtin_bit_cast(unsigned, f);
    u = (u + 0x7FFF + ((u >> 16) & 1)) >> 16;   // round-to-nearest-even
    return (unsigned short)u;
}
__device__ __forceinline__ float bf2f(unsigned short h) {
    unsigned u = ((unsigned)h) << 16;
    return __builtin_bit_cast(float, u);
}
// HW RNE pack: dst.lo = bf16(a), dst.hi = bf16(b)
__device__ __forceinline__ unsigned cvtpk(float a, float b) {
    unsigned r;
    asm("v_cvt_pk_bf16_f32 %0, %1, %2" : "=v"(r) : "v"(a), "v"(b));
    return r;
}

// ---------------------------------------------------------------------------
// Rolling-row MFMA conv, stride 1, Hin==Hout==H, 32 couts total, half-split:
// wave (wid&1) computes couts [hh*16, hh*16+16). 4-slot row window,
// distance-1 prefetch: iter s loads row s+2, computes row s. Pass-loop
// outer; per-pass A cached in 9 VGPR frags. slot(rel row r) = (r+1)&3.
template<int NPASS, bool LRELU, int YS>
__global__ __launch_bounds__(BDIM, 3)
void convr_k(const short* __restrict__ in0, const short* __restrict__ in1,
             const short* __restrict__ wf,   // [pass][tap][2][lane][8] bf16
             const float* __restrict__ bias,
             short* __restrict__ out, int H, int W)
{
    const int lane = threadIdx.x & 63;
    const int wid  = blockIdx.x * 4 + (threadIdx.x >> 6);
    const int hh   = wid & 1;          // cout half
    const int sw   = wid >> 1;         // spatial wave id
    const int segs = W >> 4;
    const int strips = (H / YS) * segs;
    const int b = sw / strips;
    int r = sw - b * strips;
    const int ys = r / segs;
    const int y0 = ys * YS;
    const int x0 = (r - ys * segs) * 16;
    const int lp = lane & 15;
    const int g  = lane >> 4;

    int colOff[3]; bool colOk[3];
#pragma unroll
    for (int tx = 0; tx < 3; ++tx) {
        const int ix = x0 + lp + tx - 1;
        colOk[tx] = (unsigned)ix < (unsigned)W;
        colOff[tx] = min(max(ix, 0), W - 1) * 32 + g * 8;
    }

    const size_t inPlane = (size_t)H * W * 32;
    const short8v zero = {};

    f32x4 acc[YS];
#pragma unroll
    for (int s = 0; s < YS; ++s) acc[s] = (f32x4){0.f, 0.f, 0.f, 0.f};

#pragma unroll
    for (int pass = 0; pass < NPASS; ++pass) {
        const short* inp = (pass == 0 ? in0 : in1) + (size_t)b * inPlane;

        // this pass's A-frags for our cout half (9 x 4 VGPR)
        short8v awc[9];
#pragma unroll
        for (int t = 0; t < 9; ++t)
            awc[t] = *(const short8v*)(
                wf + ((((size_t)pass * 9 + t) * 2 + hh) * 64 + lane) * 8);

        short8v win[4][3];

#define LDR(SLOT, IY) do {                                                    \
        const int iy_ = (IY);                                                 \
        const bool rok_ = (unsigned)iy_ < (unsigned)H;                        \
        const int ro_ = min(max(iy_, 0), H - 1) * W;                          \
        _Pragma("unroll")                                                     \
        for (int tx = 0; tx < 3; ++tx) {                                      \
            short8v v_ = *(const short8v*)(inp + (size_t)ro_ * 32 + colOff[tx]); \
            win[SLOT][tx] = (rok_ & colOk[tx]) ? v_ : zero;                   \
        }                                                                     \
    } while (0)

        LDR(0, y0 - 1);     // rel row -1
        LDR(1, y0);         // rel row  0
        LDR(2, y0 + 1);     // rel row  1

#pragma unroll
        for (int s = 0; s < YS; ++s) {
            if (s <= YS - 2)
                LDR((s + 3) & 3, y0 + s + 2);   // rel row s+2, used at iter s+1
#pragma unroll
            for (int ty = 0; ty < 3; ++ty) {
#pragma unroll
                for (int tx = 0; tx < 3; ++tx) {
                    acc[s] = __builtin_amdgcn_mfma_f32_16x16x32_bf16(
                        awc[ty * 3 + tx], win[(s + ty) & 3][tx], acc[s], 0, 0, 0);
                }
            }
        }
#undef LDR
    }

#pragma unroll
    for (int s = 0; s < YS; ++s) {
        short* op = out + (((size_t)b * H + (y0 + s)) * W + x0 + lp) * 32;
        float v[4];
#pragma unroll
        for (int j = 0; j < 4; ++j) {
            float t = acc[s][j] + bias[hh * 16 + g * 4 + j];
            if (LRELU) t = (t >= 0.f) ? t : 0.1f * t;
            v[j] = t;
        }
        uint2 st;
        st.x = cvtpk(v[0], v[1]);
        st.y = cvtpk(v[2], v[3]);
        *(uint2*)(op + hh * 16 + g * 4) = st;
    }
}

// ---------------------------------------------------------------------------
// Upfront-9-tap MFMA conv (small resolutions / strided).
template<int NPASS, int NHALF, int STRIDE, bool LRELU>
__global__ __launch_bounds__(BDIM, 4)
void convm_k(const short* __restrict__ in0, const short* __restrict__ in1,
             const short* __restrict__ wf,
             const float* __restrict__ bias,
             short* __restrict__ out,
             int Hin, int Win, int Hout, int Wout, int OCS)
{
    const int lane = threadIdx.x & 63;
    const int wid  = blockIdx.x * 4 + (threadIdx.x >> 6);
    const int segs = Wout >> 4;
    const int b  = wid / (Hout * segs);
    int r = wid - b * (Hout * segs);
    const int oy = r / segs;
    const int x0 = (r - oy * segs) * 16;
    const int lp = lane & 15;
    const int g  = lane >> 4;

    int rowOff[3]; bool rowOk[3];
#pragma unroll
    for (int ty = 0; ty < 3; ++ty) {
        const int iy = oy * STRIDE + ty - 1;
        rowOk[ty] = (unsigned)iy < (unsigned)Hin;
        rowOff[ty] = min(max(iy, 0), Hin - 1) * Win;
    }
    int colOff[3]; bool colOk[3];
#pragma unroll
    for (int tx = 0; tx < 3; ++tx) {
        const int ix = (x0 + lp) * STRIDE + tx - 1;
        colOk[tx] = (unsigned)ix < (unsigned)Win;
        colOff[tx] = min(max(ix, 0), Win - 1) * 32 + g * 8;
    }

    f32x4 acc[NHALF];
#pragma unroll
    for (int h = 0; h < NHALF; ++h) acc[h] = (f32x4){0.f, 0.f, 0.f, 0.f};

    const size_t inPlane = (size_t)Hin * Win * 32;
    const short8v zero = {};

#pragma unroll
    for (int pass = 0; pass < NPASS; ++pass) {
        const short* inp = (pass == 0 ? in0 : in1) + (size_t)b * inPlane;

        short8v bv[9];
#pragma unroll
        for (int t = 0; t < 9; ++t) {
            const int ty = t / 3, tx = t % 3;
            short8v v = *(const short8v*)(inp + (size_t)rowOff[ty] * 32 + colOff[tx]);
            bv[t] = (rowOk[ty] & colOk[tx]) ? v : zero;
        }
#pragma unroll
        for (int t = 0; t < 9; ++t) {
#pragma unroll
            for (int h = 0; h < NHALF; ++h) {
                short8v av = *(const short8v*)(
                    wf + ((((size_t)pass * 9 + t) * NHALF + h) * 64 + lane) * 8);
                acc[h] = __builtin_amdgcn_mfma_f32_16x16x32_bf16(av, bv[t], acc[h], 0, 0, 0);
            }
        }
    }

    short* op = out + (((size_t)b * Hout + oy) * Wout + x0 + lp) * OCS;
#pragma unroll
    for (int h = 0; h < NHALF; ++h) {
        const int co0 = h * 16 + g * 4;
        ushort4 st;
#pragma unroll
        for (int j = 0; j < 4; ++j) {
            float v = acc[h][j] + bias[co0 + j];
            if (LRELU) v = (v >= 0.f) ? v : 0.1f * v;
            ((unsigned short*)&st)[j] = f2bf(v);
        }
        *(ushort4*)(op + co0) = st;
    }
}

// ---------------------------------------------------------------------------
// Weight prep: [O][I][3][3] fp32 -> fragment layout bf16 [pass][t][h][lane][8].
struct WPArgs {
    const float* src[11];
    int off[11];      // dst offset in shorts
    int npass[11], nhalf[11], O[11];
};

__global__ __launch_bounds__(BDIM)
void wprep_k(WPArgs a, short* __restrict__ wbase)
{
    const int z = blockIdx.z;
    const int n = a.npass[z] * 9 * a.nhalf[z] * 512;
    const int idx = blockIdx.x * BDIM + threadIdx.x;
    if (idx >= n) return;
    const int j = idx & 7;
    const int l = (idx >> 3) & 63;
    int r = idx >> 9;
    const int h = r % a.nhalf[z]; r /= a.nhalf[z];
    const int t = r % 9;
    const int pass = r / 9;
    const int I = a.npass[z] * 32;
    const int cout = h * 16 + (l & 15);
    const int cin  = pass * 32 + (l >> 4) * 8 + j;
    float v = (cout < a.O[z]) ? a.src[z][((size_t)cout * I + cin) * 9 + t] : 0.f;
    wbase[a.off[z] + idx] = (short)f2bf(v);
}

// dcn weights [32o][32i][3][3] -> [tap][half][lane][8] bf16 frags
__global__ __launch_bounds__(BDIM)
void wdp_k(const float* __restrict__ w, short* __restrict__ dst)
{
    const int idx = blockIdx.x * BDIM + threadIdx.x;
    if (idx >= 9 * 2 * 64 * 8) return;
    const int j = idx & 7;
    const int l = (idx >> 3) & 63;
    const int h = (idx >> 9) & 1;
    const int k = idx >> 10;
    const int cout = h * 16 + (l & 15);
    const int cin  = (l >> 4) * 8 + j;
    dst[idx] = (short)f2bf(w[((size_t)cout * 32 + cin) * 9 + k]);
}

// fea NCHW fp32 -> NHWC bf16 (two tensors in one launch via z)
__global__ __launch_bounds__(BDIM)
void cvtnhwc_k(const float* __restrict__ s0, const float* __restrict__ s1,
               short* __restrict__ d0, short* __restrict__ d1, int H, int W)
{
    const float* s = blockIdx.z ? s1 : s0;
    short* d = blockIdx.z ? d1 : d0;
    const int idx = blockIdx.x * BDIM + threadIdx.x;
    if (idx >= 4 * 32 * H * W) return;
    const int c = idx & 31;
    int t = idx >> 5;
    const int x = t % W; t /= W;
    const int y = t % H;
    const int b = t / H;
    d[idx] = (short)f2bf(s[(((size_t)b * 32 + c) * H + y) * W + x]);
}

// Bilinear 2x upsample, NHWC bf16, half-pixel centers, edge clamp.
__global__ __launch_bounds__(BDIM)
void up2b_k(const short* __restrict__ in, short* __restrict__ out,
            int Hin, int Win)
{
    const int Hout = 2 * Hin, Wout = 2 * Win;
    const int idx = blockIdx.x * BDIM + threadIdx.x;
    if (idx >= 4 * Hout * Wout * 4) return;
    const int cg = idx & 3;
    int t = idx >> 2;
    const int x = t % Wout; t /= Wout;
    const int y = t % Hout;
    const int b = t / Hout;

    const float sy = (y + 0.5f) * 0.5f - 0.5f;
    const float sx = (x + 0.5f) * 0.5f - 0.5f;
    const float y0f = floorf(sy), x0f = floorf(sx);
    const float wy = sy - y0f, wx = sx - x0f;
    const int y0 = (int)y0f, x0 = (int)x0f;
    const int y0c = min(max(y0, 0), Hin - 1);
    const int y1c = min(max(y0 + 1, 0), Hin - 1);
    const int x0c = min(max(x0, 0), Win - 1);
    const int x1c = min(max(x0 + 1, 0), Win - 1);

    const short* base = in + (size_t)b * Hin * Win * 32 + cg * 8;
    short8v v00 = *(const short8v*)(base + ((size_t)y0c * Win + x0c) * 32);
    short8v v01 = *(const short8v*)(base + ((size_t)y0c * Win + x1c) * 32);
    short8v v10 = *(const short8v*)(base + ((size_t)y1c * Win + x0c) * 32);
    short8v v11 = *(const short8v*)(base + ((size_t)y1c * Win + x1c) * 32);

    short8v o;
#pragma unroll
    for (int j = 0; j < 8; ++j) {
        float f = (1.f - wy) * ((1.f - wx) * bf2f((unsigned short)v00[j]) +
                                wx * bf2f((unsigned short)v01[j]))
                + wy * ((1.f - wx) * bf2f((unsigned short)v10[j]) +
                        wx * bf2f((unsigned short)v11[j]));
        o[j] = (short)f2bf(f);
    }
    short* op = out + (size_t)b * Hout * Wout * 32 + ((size_t)y * Wout + x) * 32 + cg * 8;
    *(short8v*)op = o;
}

// ---------------------------------------------------------------------------
// Fused conv_om + modulated deformable conv (DCNv2) on MFMA.
// Phase 1: om = conv3x3(base_offset) on MFMA -> LDS [wave][16][116]
// (wave-private, padded). Phase 2: per tap address -> 4 gathers -> blend
// -> HW cvt_pk bf16 pack -> 2 MFMAs.
__global__ __launch_bounds__(BDIM, 4)
void dcnm_k(const short* __restrict__ xb,    // fea2 NHWC bf16 [B][H][W][32]
            const short* __restrict__ bo,    // base_offset NHWC bf16
            const short* __restrict__ wfo,   // om A-frags [9][7][64][8]
            const float* __restrict__ obias, // om bias (108)
            const short* __restrict__ wfd,   // dcn A-frags [9][2][64][8]
            const float* __restrict__ bias,  // dcn bias (32)
            float* __restrict__ out, int H, int W)
{
    __shared__ unsigned short omld[4][16][116];   // padded stride

    const int lane = threadIdx.x & 63;
    const int wv   = threadIdx.x >> 6;
    const int wid  = blockIdx.x * 4 + wv;
    const int segs = W >> 4;
    const int b = wid / (H * segs);
    int r = wid - b * (H * segs);
    const int y = r / segs;
    const int x0 = (r - y * segs) * 16;
    const int lp = lane & 15;
    const int g  = lane >> 4;
    const int x  = x0 + lp;
    const size_t plane = (size_t)H * W;
    const short8v zero = {};

    // ---------------- phase 1: om = conv_om(base_offset) ----------------
    {
        int rowOff[3]; bool rowOk[3];
#pragma unroll
        for (int ty = 0; ty < 3; ++ty) {
            const int iy = y + ty - 1;
            rowOk[ty] = (unsigned)iy < (unsigned)H;
            rowOff[ty] = min(max(iy, 0), H - 1) * W;
        }
        int colOff[3]; bool colOk[3];
#pragma unroll
        for (int tx = 0; tx < 3; ++tx) {
            const int ix = x + tx - 1;
            colOk[tx] = (unsigned)ix < (unsigned)W;
            colOff[tx] = min(max(ix, 0), W - 1) * 32 + g * 8;
        }
        const short* inp = bo + (size_t)b * plane * 32;
        short8v bv[9];
#pragma unroll
        for (int t = 0; t < 9; ++t) {
            const int ty = t / 3, tx = t % 3;
            short8v v = *(const short8v*)(inp + (size_t)rowOff[ty] * 32 + colOff[tx]);
            bv[t] = (rowOk[ty] & colOk[tx]) ? v : zero;
        }
        f32x4 acc[7];
#pragma unroll
        for (int h = 0; h < 7; ++h) acc[h] = (f32x4){0.f, 0.f, 0.f, 0.f};
#pragma unroll
        for (int t = 0; t < 9; ++t) {
#pragma unroll
            for (int h = 0; h < 7; ++h) {
                short8v av = *(const short8v*)(wfo + (((size_t)t * 7 + h) * 64 + lane) * 8);
                acc[h] = __builtin_amdgcn_mfma_f32_16x16x32_bf16(av, bv[t], acc[h], 0, 0, 0);
            }
        }
#pragma unroll
        for (int h = 0; h < 7; ++h) {
            const int co0 = h * 16 + g * 4;
            float t0 = acc[h][0] + obias[min(co0 + 0, 107)];
            float t1 = acc[h][1] + obias[min(co0 + 1, 107)];
            float t2 = acc[h][2] + obias[min(co0 + 2, 107)];
            float t3 = acc[h][3] + obias[min(co0 + 3, 107)];
            uint2 st;
            st.x = cvtpk(t0, t1);
            st.y = cvtpk(t2, t3);
            *(uint2*)&omld[wv][lp][co0] = st;
        }
    }
    // wave-private LDS: in-wave ds ordering + compiler lgkmcnt suffice

    // ---------------- phase 2: deformable sampling + PV ----------------
    f32x4 p0 = (f32x4){0.f, 0.f, 0.f, 0.f};
    f32x4 p1 = (f32x4){0.f, 0.f, 0.f, 0.f};
    const short* xbb = xb + (size_t)b * plane * 32 + g * 8;

#pragma unroll
    for (int k = 0; k < 9; ++k) {
        const float offy = bf2f(omld[wv][lp][g * 9 + k]);
        const float offx = bf2f(omld[wv][lp][36 + g * 9 + k]);
        const float ml   = bf2f(omld[wv][lp][72 + g * 9 + k]);
        const float m = 1.f / (1.f + __expf(-ml));

        const float py = offy + (float)y + (float)(k / 3 - 1);
        const float px = offx + (float)x + (float)(k % 3 - 1);
        const float y0f = floorf(py), x0f = floorf(px);
        const int y0 = (int)y0f, x0i = (int)x0f;
        const float wy1 = py - y0f, wx1 = px - x0f;
        const float wy0 = 1.f - wy1, wx0 = 1.f - wx1;

        const bool y0ok = (unsigned)y0 < (unsigned)H;
        const bool y1ok = (unsigned)(y0 + 1) < (unsigned)H;
        const bool x0ok = (unsigned)x0i < (unsigned)W;
        const bool x1ok = (unsigned)(x0i + 1) < (unsigned)W;
        const int y0c = min(max(y0, 0), H - 1);
        const int y1c = min(max(y0 + 1, 0), H - 1);
        const int x0c = min(max(x0i, 0), W - 1);
        const int x1c = min(max(x0i + 1, 0), W - 1);

        const float w00 = wy0 * wx0 * ((y0ok && x0ok) ? 1.f : 0.f) * m;
        const float w01 = wy0 * wx1 * ((y0ok && x1ok) ? 1.f : 0.f) * m;
        const float w10 = wy1 * wx0 * ((y1ok && x0ok) ? 1.f : 0.f) * m;
        const float w11 = wy1 * wx1 * ((y1ok && x1ok) ? 1.f : 0.f) * m;

        short8v v00 = *(const short8v*)(xbb + ((size_t)y0c * W + x0c) * 32);
        short8v v01 = *(const short8v*)(xbb + ((size_t)y0c * W + x1c) * 32);
        short8v v10 = *(const short8v*)(xbb + ((size_t)y1c * W + x0c) * 32);
        short8v v11 = *(const short8v*)(xbb + ((size_t)y1c * W + x1c) * 32);

        float s[8];
#pragma unroll
        for (int j = 0; j < 8; ++j) {
            s[j] = w00 * bf2f((unsigned short)v00[j])
                 + w01 * bf2f((unsigned short)v01[j])
                 + w10 * bf2f((unsigned short)v10[j])
                 + w11 * bf2f((unsigned short)v11[j]);
        }
        short8v bvv;
        unsigned* bp = (unsigned*)&bvv;
        bp[0] = cvtpk(s[0], s[1]);
        bp[1] = cvtpk(s[2], s[3]);
        bp[2] = cvtpk(s[4], s[5]);
        bp[3] = cvtpk(s[6], s[7]);

        short8v a0 = *(const short8v*)(wfd + (((size_t)k * 2 + 0) * 64 + lane) * 8);
        short8v a1 = *(const short8v*)(wfd + (((size_t)k * 2 + 1) * 64 + lane) * 8);
        p0 = __builtin_amdgcn_mfma_f32_16x16x32_bf16(a0, bvv, p0, 0, 0, 0);
        p1 = __builtin_amdgcn_mfma_f32_16x16x32_bf16(a1, bvv, p1, 0, 0, 0);
    }

    float* op = out + (size_t)b * 32 * plane + (size_t)y * W + x;
#pragma unroll
    for (int j = 0; j < 4; ++j) {
        const int co0 = g * 4 + j;
        const int co1 = 16 + g * 4 + j;
        op[(size_t)co0 * plane] = p0[j] + bias[co0];
        op[(size_t)co1 * plane] = p1[j] + bias[co1];
    }
}

// ---------------------------------------------------------------------------

extern "C" void kernel_launch(void* const* d_in, const int* in_sizes, int n_in,
                              void* d_out, int out_size, void* d_ws, size_t ws_size,
                              hipStream_t stream)
{
    const float* fea1  = (const float*)d_in[0];
    const float* fea2  = (const float*)d_in[1];
    const float* w1_1  = (const float*)d_in[2];  const float* b1_1 = (const float*)d_in[3];
    const float* w2_1  = (const float*)d_in[4];  const float* b2_1 = (const float*)d_in[5];
    const float* w3_1  = (const float*)d_in[6];  const float* b3_1 = (const float*)d_in[7];
    const float* w4_1  = (const float*)d_in[8];  const float* b4_1 = (const float*)d_in[9];
    const float* w6_1  = (const float*)d_in[10]; const float* b6_1 = (const float*)d_in[11];
    const float* w7_1  = (const float*)d_in[12]; const float* b7_1 = (const float*)d_in[13];
    const float* w1_2  = (const float*)d_in[14]; const float* b1_2 = (const float*)d_in[15];
    const float* w2_2  = (const float*)d_in[16]; const float* b2_2 = (const float*)d_in[17];
    const float* w3_2  = (const float*)d_in[18]; const float* b3_2 = (const float*)d_in[19];
    const float* w4_2  = (const float*)d_in[20]; const float* b4_2 = (const float*)d_in[21];
    const float* w_om  = (const float*)d_in[22]; const float* b_om = (const float*)d_in[23];
    const float* w_dcn = (const float*)d_in[24]; const float* b_dcn= (const float*)d_in[25];

    const int H = 192, W = 192;
    char* ws = (char*)d_ws;

    // byte offsets; fea2b stays live to the end (dcnm samples it)
    short* fea1b = (short*)(ws + 0);          // bf16 NHWC 192  (9.44 MB)
    short* fea2b = (short*)(ws + 9437184);    // LIVE TO END
    short* bufA  = (short*)(ws + 18874368);   // off      192
    short* bufB  = (short*)(ws + 28311552);   // off1     192 (lives to conv3_2)
    short* bufC  = (short*)(ws + 0);          // off2a    96  (fea1b dead)
    short* bufD  = (short*)(ws + 2359296);    // off2     96
    short* bufE  = (short*)(ws + 4718592);    // off3a    48
    short* bufF  = (short*)(ws + 5308416);    // off3     48
    short* bufG  = (short*)(ws + 5898240);    // up96     96
    short* bufH  = (short*)(ws + 0);          // conv1_2 out 96 (bufC dead)
    short* bufI  = (short*)(ws + 4718592);    // conv2_2 out 96 (E/F dead)
    short* bufJ  = (short*)(ws + 37748736);   // up192
    short* bufK  = (short*)(ws + 18874368);   // conv3_2 out (bufA dead)
    short* bufL  = (short*)(ws + 0);          // base_offset 192 (H/D/I dead)
    short* wfrag = (short*)(ws + 70778880);   // conv weight frags (304128 B)
    short* wfdcn = (short*)(ws + 71083008);   // dcn weight frags (18432 B)

    // fragment offsets in shorts per conv (om entry has nh=7 -> 32256 shorts)
    const int WOFF[11] = {0, 18432, 27648, 36864, 46080, 55296,
                          64512, 82944, 92160, 110592, 119808};

    dim3 blk(BDIM, 1, 1);

    // 0. weight prep + input conversions
    {
        WPArgs a;
        const float* srcs[11] = {w1_1, w2_1, w3_1, w4_1, w6_1, w7_1,
                                 w1_2, w2_2, w3_2, w4_2, w_om};
        const int NP[11] = {2,1,1,1,1,1,2,1,2,1,1};
        const int NH[11] = {2,2,2,2,2,2,2,2,2,2,7};
        const int Os[11] = {32,32,32,32,32,32,32,32,32,32,108};
        for (int i = 0; i < 11; ++i) {
            a.src[i] = srcs[i]; a.off[i] = WOFF[i];
            a.npass[i] = NP[i]; a.nhalf[i] = NH[i]; a.O[i] = Os[i];
        }
        wprep_k<<<dim3(126, 1, 11), blk, 0, stream>>>(a, wfrag);
        cvtnhwc_k<<<dim3(18432, 1, 2), blk, 0, stream>>>(fea1, fea2, fea1b, fea2b, H, W);
        wdp_k<<<dim3(36), blk, 0, stream>>>(w_dcn, wfdcn);
    }

    // 192-res rolling convs: waves = B*(H/4)*12*2 halves = 4608 -> 1152 blocks
    // 1. off = lrelu(conv1_1(cat(fea1, fea2)))           192  [rolling d1]
    convr_k<2,true,4><<<dim3(1152), blk, 0, stream>>>(
        fea1b, fea2b, wfrag + WOFF[0], b1_1, bufA, 192, 192);
    // 2. off1 = lrelu(conv2_1(off))                      192
    convr_k<1,true,4><<<dim3(1152), blk, 0, stream>>>(
        bufA, nullptr, wfrag + WOFF[1], b2_1, bufB, 192, 192);
    // 3. off2a = lrelu(conv3_1(off1, s2))                96
    convm_k<1,2,2,true><<<dim3(576), blk, 0, stream>>>(
        bufB, nullptr, wfrag + WOFF[2], b3_1, bufC, 192,192,96,96, 32);
    // 4. off2 = lrelu(conv4_1(off2a))                    96
    convm_k<1,2,1,true><<<dim3(576), blk, 0, stream>>>(
        bufC, nullptr, wfrag + WOFF[3], b4_1, bufD, 96,96,96,96, 32);
    // 5. off3a = lrelu(conv6_1(off2, s2))                48
    convm_k<1,2,2,true><<<dim3(144), blk, 0, stream>>>(
        bufD, nullptr, wfrag + WOFF[4], b6_1, bufE, 96,96,48,48, 32);
    // 6. off3 = lrelu(conv7_1(off3a))                    48
    convm_k<1,2,1,true><<<dim3(144), blk, 0, stream>>>(
        bufE, nullptr, wfrag + WOFF[5], b7_1, bufF, 48,48,48,48, 32);
    // 7. up96 = up2(off3)
    up2b_k<<<dim3(576), blk, 0, stream>>>(bufF, bufG, 48, 48);
    // 8. t = lrelu(conv1_2(cat(up96, off2)))             96
    convm_k<2,2,1,true><<<dim3(576), blk, 0, stream>>>(
        bufG, bufD, wfrag + WOFF[6], b1_2, bufH, 96,96,96,96, 32);
    // 9. t2 = lrelu(conv2_2(t))                          96
    convm_k<1,2,1,true><<<dim3(576), blk, 0, stream>>>(
        bufH, nullptr, wfrag + WOFF[7], b2_2, bufI, 96,96,96,96, 32);
    // 10. up192 = up2(t2)
    up2b_k<<<dim3(2304), blk, 0, stream>>>(bufI, bufJ, 96, 96);
    // 11. off = lrelu(conv3_2(cat(up192, off1)))         192
    convr_k<2,true,4><<<dim3(1152), blk, 0, stream>>>(
        bufJ, bufB, wfrag + WOFF[8], b3_2, bufK, 192, 192);
    // 12. base_offset = conv4_2(off)    (no lrelu)       192
    convr_k<1,false,4><<<dim3(1152), blk, 0, stream>>>(
        bufK, nullptr, wfrag + WOFF[9], b4_2, bufL, 192, 192);
    // 13. out = deform_conv(fea2, conv_om(base_offset))  [fused]
    dcnm_k<<<dim3(2304), blk, 0, stream>>>(
        fea2b, bufL, wfrag + WOFF[10], b_om, wfdcn, b_dcn, (float*)d_out, H, W);
}